// Round 5
// baseline (701.388 us; speedup 1.0000x reference)
//
#include <hip/hip_runtime.h>
#include <cstdint>

// 2-layer GAT, PyG GATConv semantics (concat heads, self-loops, segment softmax).
// R5: compact CSR counting-sort bucket build (hist + 1-WG scan + scatter into
// 6.8MB ccol) replaces the padded CAP-table scatter whose random dword writes
// caused ~16x HBM write amplification (99.6MB for 6.8MB payload).
// GEMM (R4 LDS-tiled) and fused node aggregation unchanged.
// Softmax max-subtraction omitted: shift-invariant, |e| <= ~10 so exp() safe in f32.

__device__ __forceinline__ float lrelu(float v) { return fmaxf(v, 0.2f * v); }

__global__ void ifill_kernel(int* __restrict__ p, int v, int n) {
  int i = blockIdx.x * blockDim.x + threadIdx.x;
  if (i < n) p[i] = v;
}

// In-degree histogram over real edges (deg pre-initialized to 1 = self-loop).
__global__ void hist_kernel(const int* __restrict__ edst, int E,
                            int* __restrict__ deg) {
  int e = blockIdx.x * blockDim.x + threadIdx.x;
  if (e < E) atomicAdd(&deg[edst[e]], 1);
}

// Single-workgroup exclusive scan of deg[0..n) -> start[] and cursor[] (copy).
// 1024 threads x ~98 sequential elements each; Hillis-Steele over partials.
__global__ __launch_bounds__(1024) void scan_kernel(const int* __restrict__ deg,
                                                    int* __restrict__ start,
                                                    int* __restrict__ cursor,
                                                    int n) {
  __shared__ int part[1024];
  const int t = threadIdx.x;
  const int chunk = (n + 1023) / 1024;
  const int lo = t * chunk;
  const int hi = (lo + chunk < n) ? lo + chunk : n;
  int s = 0;
  for (int i = lo; i < hi; ++i) s += deg[i];
  part[t] = s;
  __syncthreads();
  for (int off = 1; off < 1024; off <<= 1) {
    int u = (t >= off) ? part[t - off] : 0;
    __syncthreads();
    part[t] += u;
    __syncthreads();
  }
  int running = part[t] - s;  // exclusive prefix of this thread's chunk
  for (int i = lo; i < hi; ++i) {
    start[i] = running;
    cursor[i] = running;
    running += deg[i];
  }
}

// Scatter src ids into compact CSR col array (incl. self-loops at e >= E).
// After this kernel, cursor[d] == start[d] + deg[d] == end offset.
__global__ void scatter_csr(const int* __restrict__ esrc,
                            const int* __restrict__ edst, int E, int n,
                            int* __restrict__ cursor, int* __restrict__ ccol) {
  int e = blockIdx.x * blockDim.x + threadIdx.x;
  int tot = E + n;
  if (e >= tot) return;
  int si, di;
  if (e < E) { si = esrc[e]; di = edst[e]; } else { si = e - E; di = si; }
  int pos = atomicAdd(&cursor[di], 1);
  ccol[pos] = si;
}

// h[n][64] = x[n][K] @ W[K][64]; a_s[n][h] = sum_c h*att_src, a_d likewise.
// Tiled GEMM: block = 64 rows x 64 cols, BK=64 chunks staged in LDS.
// Thread (ty,tx) = (tid>>4, tid&15) computes rows ty*4..+3, cols tx*4..+3.
template <int K>
__global__ __launch_bounds__(256) void gemm_att(
    const float* __restrict__ x, const float* __restrict__ W,
    const float* __restrict__ att_src, const float* __restrict__ att_dst,
    float* __restrict__ h, float* __restrict__ as_, float* __restrict__ ad_,
    int n) {
  __shared__ float xs[64 * 68];  // x tile [row][k], stride 68
  __shared__ float ws[64 * 64];  // W chunk [k][col]
  const int tid = threadIdx.x;
  const int ty = tid >> 4;
  const int tx = tid & 15;
  const int row0 = blockIdx.x * 64;
  const int sr = tid >> 4;
  const int sc = tid & 15;

  float acc[4][4] = {{0.f}};

  for (int c = 0; c < K; c += 64) {
    __syncthreads();
    {  // stage W chunk: linear float4 copy
      const float4* wsrc = (const float4*)(W + (long long)c * 64);
      float4* wdst = (float4*)ws;
#pragma unroll
      for (int j = 0; j < 4; ++j) wdst[tid + j * 256] = wsrc[tid + j * 256];
    }
#pragma unroll
    for (int j = 0; j < 4; ++j) {  // stage x tile (clamped tail rows)
      int r = sr + j * 16;
      int rr = row0 + r;
      if (rr > n - 1) rr = n - 1;
      float4 v = *(const float4*)(x + (long long)rr * K + c + sc * 4);
      *(float4*)(xs + r * 68 + sc * 4) = v;
    }
    __syncthreads();
#pragma unroll 2
    for (int kk = 0; kk < 64; kk += 4) {
      float4 xv[4], wv[4];
#pragma unroll
      for (int i = 0; i < 4; ++i)
        xv[i] = *(const float4*)(xs + (ty * 4 + i) * 68 + kk);
#pragma unroll
      for (int q = 0; q < 4; ++q)
        wv[q] = *(const float4*)(ws + (kk + q) * 64 + tx * 4);
#pragma unroll
      for (int q = 0; q < 4; ++q) {
#pragma unroll
        for (int i = 0; i < 4; ++i) {
          float xq = (q == 0) ? xv[i].x : (q == 1) ? xv[i].y : (q == 2) ? xv[i].z : xv[i].w;
          acc[i][0] = fmaf(xq, wv[q].x, acc[i][0]);
          acc[i][1] = fmaf(xq, wv[q].y, acc[i][1]);
          acc[i][2] = fmaf(xq, wv[q].z, acc[i][2]);
          acc[i][3] = fmaf(xq, wv[q].w, acc[i][3]);
        }
      }
    }
  }

  // Epilogue: h store + per-head att dots (reduce over 4 lanes sharing a head).
  const float4 atts = *(const float4*)(att_src + tx * 4);
  const float4 attd = *(const float4*)(att_dst + tx * 4);
  const int head = tx >> 2;
#pragma unroll
  for (int i = 0; i < 4; ++i) {
    int row = row0 + ty * 4 + i;
    if (row >= n) break;
    float4 hv = make_float4(acc[i][0], acc[i][1], acc[i][2], acc[i][3]);
    *(float4*)(h + (long long)row * 64 + tx * 4) = hv;
    float s = acc[i][0] * atts.x + acc[i][1] * atts.y + acc[i][2] * atts.z + acc[i][3] * atts.w;
    float d = acc[i][0] * attd.x + acc[i][1] * attd.y + acc[i][2] * attd.z + acc[i][3] * attd.w;
    s += __shfl_xor(s, 1);
    s += __shfl_xor(s, 2);
    d += __shfl_xor(d, 1);
    d += __shfl_xor(d, 2);
    if ((tx & 3) == 0) {
      as_[(long long)row * 4 + head] = s;
      ad_[(long long)row * 4 + head] = d;
    }
  }
}

// One wave per dst node; lane = channel. Single pass accumulates
// num = sum p*h[src] and den = sum p in registers, then out = num/den + b (+relu).
// CSR: edges for node are ccol[start[node] .. cursor[node]) (cursor==end after scatter).
__global__ __launch_bounds__(256) void node_agg_kernel(
    const int* __restrict__ ccol, const int* __restrict__ start,
    const int* __restrict__ endp,
    const float* __restrict__ as_, const float* __restrict__ ad_,
    const float* __restrict__ h, const float* __restrict__ bias,
    float* __restrict__ out, int n, int do_relu) {
  int node = blockIdx.x * 4 + (threadIdx.x >> 6);
  if (node >= n) return;
  const int lane = threadIdx.x & 63;
  const int hh = lane >> 4;
  const float adv = ad_[(long long)node * 4 + hh];
  const int s0i = start[node];
  const int e0i = endp[node];
  const int d = e0i - s0i;
  const int* cp = ccol + s0i;
  float acc = 0.f, den = 0.f;
  int i = 0;
  for (; i + 2 <= d; i += 2) {  // 2x unroll for load ILP
    int s0 = cp[i], s1 = cp[i + 1];
    float p0 = __expf(lrelu(as_[(long long)s0 * 4 + hh] + adv));
    float p1 = __expf(lrelu(as_[(long long)s1 * 4 + hh] + adv));
    float h0 = h[(long long)s0 * 64 + lane];
    float h1 = h[(long long)s1 * 64 + lane];
    den += p0 + p1;
    acc = fmaf(p0, h0, acc);
    acc = fmaf(p1, h1, acc);
  }
  if (i < d) {
    int s0 = cp[i];
    float p0 = __expf(lrelu(as_[(long long)s0 * 4 + hh] + adv));
    den += p0;
    acc = fmaf(p0, h[(long long)s0 * 64 + lane], acc);
  }
  float v = acc / (den + 1e-16f) + bias[lane];
  out[(long long)node * 64 + lane] = do_relu ? fmaxf(v, 0.f) : v;
}

extern "C" void kernel_launch(void* const* d_in, const int* in_sizes, int n_in,
                              void* d_out, int out_size, void* d_ws, size_t ws_size,
                              hipStream_t stream) {
  const float* x = (const float*)d_in[0];
  const int* ei = (const int*)d_in[1];
  const float* W1 = (const float*)d_in[2];
  const float* att_s1 = (const float*)d_in[3];
  const float* att_d1 = (const float*)d_in[4];
  const float* b1 = (const float*)d_in[5];
  const float* W2 = (const float*)d_in[6];
  const float* att_s2 = (const float*)d_in[7];
  const float* att_d2 = (const float*)d_in[8];
  const float* b2 = (const float*)d_in[9];

  const int n = in_sizes[0] / 256;  // 100000
  const int E = in_sizes[1] / 2;    // 1600000
  const int* esrc = ei;
  const int* edst = ei + E;

  float* wsf = (float*)d_ws;
  float* hbuf = wsf;                          // [n*64]
  float* xbuf = hbuf + (long long)n * 64;     // [n*64] layer-1 output / layer-2 input
  float* as_ = xbuf + (long long)n * 64;      // [n*4]
  float* ad_ = as_ + (long long)n * 4;        // [n*4]
  int* deg = (int*)(ad_ + (long long)n * 4);  // [n]
  int* start = deg + n;                       // [n]
  int* cursor = start + n;                    // [n]
  int* ccol = cursor + n;                     // [E+n]
  float* out = (float*)d_out;

  const int tot = E + n;
  const int eb = (tot + 255) / 256;
  const int gb = (n + 63) / 64;
  const int nb = (n + 3) / 4;

  // ---- CSR bucket build (shared by both layers) ----
  ifill_kernel<<<(n + 255) / 256, 256, 0, stream>>>(deg, 1, n);  // 1 = self-loop
  hist_kernel<<<(E + 255) / 256, 256, 0, stream>>>(edst, E, deg);
  scan_kernel<<<1, 1024, 0, stream>>>(deg, start, cursor, n);
  scatter_csr<<<eb, 256, 0, stream>>>(esrc, edst, E, n, cursor, ccol);

  // ---- layer 1 ----
  gemm_att<256><<<gb, 256, 0, stream>>>(x, W1, att_s1, att_d1, hbuf, as_, ad_, n);
  node_agg_kernel<<<nb, 256, 0, stream>>>(ccol, start, cursor, as_, ad_, hbuf, b1, xbuf, n, 1);

  // ---- layer 2 ----
  gemm_att<64><<<gb, 256, 0, stream>>>(xbuf, W2, att_s2, att_d2, hbuf, as_, ad_, n);
  node_agg_kernel<<<nb, 256, 0, stream>>>(ccol, start, cursor, as_, ad_, hbuf, b2, out, n, 0);
}

// Round 6
// 480.585 us; speedup vs baseline: 1.4594x; 1.4594x over previous
//
#include <hip/hip_runtime.h>
#include <cstdint>

// 2-layer GAT, PyG GATConv semantics (concat heads, self-loops, segment softmax).
// R6: hierarchical 3-kernel scan (block sums -> scan totals -> block-local scan
// + offset) replaces R5's single-WG scan (232us at 0.15% occupancy).
// Everything else unchanged from R5: CSR counting sort, LDS-tiled GEMM,
// fused dst-major aggregation.
// Softmax max-subtraction omitted: shift-invariant, |e| <= ~10 so exp() safe in f32.

#define SCAN_BLK 1024  // elements per scan block (256 threads x int4)

__device__ __forceinline__ float lrelu(float v) { return fmaxf(v, 0.2f * v); }

__global__ void ifill_kernel(int* __restrict__ p, int v, int n) {
  int i = blockIdx.x * blockDim.x + threadIdx.x;
  if (i < n) p[i] = v;
}

// In-degree histogram over real edges (deg pre-initialized to 1 = self-loop).
__global__ void hist_kernel(const int* __restrict__ edst, int E,
                            int* __restrict__ deg) {
  int e = blockIdx.x * blockDim.x + threadIdx.x;
  if (e < E) atomicAdd(&deg[edst[e]], 1);
}

// Per-block partial sums of SCAN_BLK-element chunks (int4-coalesced).
__global__ __launch_bounds__(256) void block_sum_kernel(
    const int* __restrict__ deg, int* __restrict__ btot, int n) {
  __shared__ int sdata[4];
  const int t = threadIdx.x;
  const int idx = blockIdx.x * SCAN_BLK + t * 4;
  int4 d = make_int4(0, 0, 0, 0);
  if (idx + 3 < n) d = *(const int4*)(deg + idx);
  else {
    if (idx + 0 < n) d.x = deg[idx + 0];
    if (idx + 1 < n) d.y = deg[idx + 1];
    if (idx + 2 < n) d.z = deg[idx + 2];
  }
  int s = d.x + d.y + d.z + d.w;
#pragma unroll
  for (int off = 1; off < 64; off <<= 1) s += __shfl_xor(s, off);
  if ((t & 63) == 0) sdata[t >> 6] = s;
  __syncthreads();
  if (t == 0) btot[blockIdx.x] = sdata[0] + sdata[1] + sdata[2] + sdata[3];
}

// Single small WG: exclusive scan of nb (<=1024) block totals in place.
__global__ __launch_bounds__(1024) void scan_btot_kernel(int* __restrict__ btot,
                                                         int nb) {
  __shared__ int part[1024];
  const int t = threadIdx.x;
  int v = (t < nb) ? btot[t] : 0;
  part[t] = v;
  __syncthreads();
  for (int off = 1; off < 1024; off <<= 1) {
    int u = (t >= off) ? part[t - off] : 0;
    __syncthreads();
    part[t] += u;
    __syncthreads();
  }
  if (t < nb) btot[t] = part[t] - v;  // exclusive
}

// Block-local exclusive scan (4 elems/thread in regs + LDS scan of thread
// sums) + global block offset; writes start[] and cursor[].
__global__ __launch_bounds__(256) void scan_write_kernel(
    const int* __restrict__ deg, const int* __restrict__ btot,
    int* __restrict__ start, int* __restrict__ cursor, int n) {
  __shared__ int part[256];
  const int t = threadIdx.x;
  const int idx = blockIdx.x * SCAN_BLK + t * 4;
  int4 d = make_int4(0, 0, 0, 0);
  if (idx + 3 < n) d = *(const int4*)(deg + idx);
  else {
    if (idx + 0 < n) d.x = deg[idx + 0];
    if (idx + 1 < n) d.y = deg[idx + 1];
    if (idx + 2 < n) d.z = deg[idx + 2];
  }
  const int s0 = d.x, s1 = s0 + d.y, s2 = s1 + d.z, s3 = s2 + d.w;
  part[t] = s3;
  __syncthreads();
#pragma unroll
  for (int off = 1; off < 256; off <<= 1) {
    int u = (t >= off) ? part[t - off] : 0;
    __syncthreads();
    part[t] += u;
    __syncthreads();
  }
  int base = part[t] - s3 + btot[blockIdx.x];  // exclusive prefix for elem idx
  if (idx + 0 < n) { start[idx + 0] = base;      cursor[idx + 0] = base; }
  if (idx + 1 < n) { start[idx + 1] = base + s0; cursor[idx + 1] = base + s0; }
  if (idx + 2 < n) { start[idx + 2] = base + s1; cursor[idx + 2] = base + s1; }
  if (idx + 3 < n) { start[idx + 3] = base + s2; cursor[idx + 3] = base + s2; }
}

// Scatter src ids into compact CSR col array (incl. self-loops at e >= E).
// After this kernel, cursor[d] == start[d] + deg[d] == end offset.
__global__ void scatter_csr(const int* __restrict__ esrc,
                            const int* __restrict__ edst, int E, int n,
                            int* __restrict__ cursor, int* __restrict__ ccol) {
  int e = blockIdx.x * blockDim.x + threadIdx.x;
  int tot = E + n;
  if (e >= tot) return;
  int si, di;
  if (e < E) { si = esrc[e]; di = edst[e]; } else { si = e - E; di = si; }
  int pos = atomicAdd(&cursor[di], 1);
  ccol[pos] = si;
}

// h[n][64] = x[n][K] @ W[K][64]; a_s[n][h] = sum_c h*att_src, a_d likewise.
// Tiled GEMM: block = 64 rows x 64 cols, BK=64 chunks staged in LDS.
template <int K>
__global__ __launch_bounds__(256) void gemm_att(
    const float* __restrict__ x, const float* __restrict__ W,
    const float* __restrict__ att_src, const float* __restrict__ att_dst,
    float* __restrict__ h, float* __restrict__ as_, float* __restrict__ ad_,
    int n) {
  __shared__ float xs[64 * 68];  // x tile [row][k], stride 68
  __shared__ float ws[64 * 64];  // W chunk [k][col]
  const int tid = threadIdx.x;
  const int ty = tid >> 4;
  const int tx = tid & 15;
  const int row0 = blockIdx.x * 64;
  const int sr = tid >> 4;
  const int sc = tid & 15;

  float acc[4][4] = {{0.f}};

  for (int c = 0; c < K; c += 64) {
    __syncthreads();
    {  // stage W chunk: linear float4 copy
      const float4* wsrc = (const float4*)(W + (long long)c * 64);
      float4* wdst = (float4*)ws;
#pragma unroll
      for (int j = 0; j < 4; ++j) wdst[tid + j * 256] = wsrc[tid + j * 256];
    }
#pragma unroll
    for (int j = 0; j < 4; ++j) {  // stage x tile (clamped tail rows)
      int r = sr + j * 16;
      int rr = row0 + r;
      if (rr > n - 1) rr = n - 1;
      float4 v = *(const float4*)(x + (long long)rr * K + c + sc * 4);
      *(float4*)(xs + r * 68 + sc * 4) = v;
    }
    __syncthreads();
#pragma unroll 2
    for (int kk = 0; kk < 64; kk += 4) {
      float4 xv[4], wv[4];
#pragma unroll
      for (int i = 0; i < 4; ++i)
        xv[i] = *(const float4*)(xs + (ty * 4 + i) * 68 + kk);
#pragma unroll
      for (int q = 0; q < 4; ++q)
        wv[q] = *(const float4*)(ws + (kk + q) * 64 + tx * 4);
#pragma unroll
      for (int q = 0; q < 4; ++q) {
#pragma unroll
        for (int i = 0; i < 4; ++i) {
          float xq = (q == 0) ? xv[i].x : (q == 1) ? xv[i].y : (q == 2) ? xv[i].z : xv[i].w;
          acc[i][0] = fmaf(xq, wv[q].x, acc[i][0]);
          acc[i][1] = fmaf(xq, wv[q].y, acc[i][1]);
          acc[i][2] = fmaf(xq, wv[q].z, acc[i][2]);
          acc[i][3] = fmaf(xq, wv[q].w, acc[i][3]);
        }
      }
    }
  }

  // Epilogue: h store + per-head att dots (reduce over 4 lanes sharing a head).
  const float4 atts = *(const float4*)(att_src + tx * 4);
  const float4 attd = *(const float4*)(att_dst + tx * 4);
  const int head = tx >> 2;
#pragma unroll
  for (int i = 0; i < 4; ++i) {
    int row = row0 + ty * 4 + i;
    if (row >= n) break;
    float4 hv = make_float4(acc[i][0], acc[i][1], acc[i][2], acc[i][3]);
    *(float4*)(h + (long long)row * 64 + tx * 4) = hv;
    float s = acc[i][0] * atts.x + acc[i][1] * atts.y + acc[i][2] * atts.z + acc[i][3] * atts.w;
    float d = acc[i][0] * attd.x + acc[i][1] * attd.y + acc[i][2] * attd.z + acc[i][3] * attd.w;
    s += __shfl_xor(s, 1);
    s += __shfl_xor(s, 2);
    d += __shfl_xor(d, 1);
    d += __shfl_xor(d, 2);
    if ((tx & 3) == 0) {
      as_[(long long)row * 4 + head] = s;
      ad_[(long long)row * 4 + head] = d;
    }
  }
}

// One wave per dst node; lane = channel. Single pass accumulates
// num = sum p*h[src] and den = sum p in registers, then out = num/den + b (+relu).
__global__ __launch_bounds__(256) void node_agg_kernel(
    const int* __restrict__ ccol, const int* __restrict__ start,
    const int* __restrict__ endp,
    const float* __restrict__ as_, const float* __restrict__ ad_,
    const float* __restrict__ h, const float* __restrict__ bias,
    float* __restrict__ out, int n, int do_relu) {
  int node = blockIdx.x * 4 + (threadIdx.x >> 6);
  if (node >= n) return;
  const int lane = threadIdx.x & 63;
  const int hh = lane >> 4;
  const float adv = ad_[(long long)node * 4 + hh];
  const int s0i = start[node];
  const int e0i = endp[node];
  const int d = e0i - s0i;
  const int* cp = ccol + s0i;
  float acc = 0.f, den = 0.f;
  int i = 0;
  for (; i + 2 <= d; i += 2) {  // 2x unroll for load ILP
    int s0 = cp[i], s1 = cp[i + 1];
    float p0 = __expf(lrelu(as_[(long long)s0 * 4 + hh] + adv));
    float p1 = __expf(lrelu(as_[(long long)s1 * 4 + hh] + adv));
    float h0 = h[(long long)s0 * 64 + lane];
    float h1 = h[(long long)s1 * 64 + lane];
    den += p0 + p1;
    acc = fmaf(p0, h0, acc);
    acc = fmaf(p1, h1, acc);
  }
  if (i < d) {
    int s0 = cp[i];
    float p0 = __expf(lrelu(as_[(long long)s0 * 4 + hh] + adv));
    den += p0;
    acc = fmaf(p0, h[(long long)s0 * 64 + lane], acc);
  }
  float v = acc / (den + 1e-16f) + bias[lane];
  out[(long long)node * 64 + lane] = do_relu ? fmaxf(v, 0.f) : v;
}

extern "C" void kernel_launch(void* const* d_in, const int* in_sizes, int n_in,
                              void* d_out, int out_size, void* d_ws, size_t ws_size,
                              hipStream_t stream) {
  const float* x = (const float*)d_in[0];
  const int* ei = (const int*)d_in[1];
  const float* W1 = (const float*)d_in[2];
  const float* att_s1 = (const float*)d_in[3];
  const float* att_d1 = (const float*)d_in[4];
  const float* b1 = (const float*)d_in[5];
  const float* W2 = (const float*)d_in[6];
  const float* att_s2 = (const float*)d_in[7];
  const float* att_d2 = (const float*)d_in[8];
  const float* b2 = (const float*)d_in[9];

  const int n = in_sizes[0] / 256;  // 100000
  const int E = in_sizes[1] / 2;    // 1600000
  const int* esrc = ei;
  const int* edst = ei + E;

  float* wsf = (float*)d_ws;
  float* hbuf = wsf;                          // [n*64]
  float* xbuf = hbuf + (long long)n * 64;     // [n*64] layer-1 output / layer-2 input
  float* as_ = xbuf + (long long)n * 64;      // [n*4]
  float* ad_ = as_ + (long long)n * 4;        // [n*4]
  int* deg = (int*)(ad_ + (long long)n * 4);  // [n]
  int* start = deg + n;                       // [n]
  int* cursor = start + n;                    // [n]
  int* btot = cursor + n;                     // [nsb]
  int* ccol = btot + 1024;                    // [E+n]
  float* out = (float*)d_out;

  const int tot = E + n;
  const int eb = (tot + 255) / 256;
  const int gb = (n + 63) / 64;
  const int nb = (n + 3) / 4;
  const int nsb = (n + SCAN_BLK - 1) / SCAN_BLK;  // 98 scan blocks

  // ---- CSR bucket build (shared by both layers) ----
  ifill_kernel<<<(n + 255) / 256, 256, 0, stream>>>(deg, 1, n);  // 1 = self-loop
  hist_kernel<<<(E + 255) / 256, 256, 0, stream>>>(edst, E, deg);
  block_sum_kernel<<<nsb, 256, 0, stream>>>(deg, btot, n);
  scan_btot_kernel<<<1, 1024, 0, stream>>>(btot, nsb);
  scan_write_kernel<<<nsb, 256, 0, stream>>>(deg, btot, start, cursor, n);
  scatter_csr<<<eb, 256, 0, stream>>>(esrc, edst, E, n, cursor, ccol);

  // ---- layer 1 ----
  gemm_att<256><<<gb, 256, 0, stream>>>(x, W1, att_s1, att_d1, hbuf, as_, ad_, n);
  node_agg_kernel<<<nb, 256, 0, stream>>>(ccol, start, cursor, as_, ad_, hbuf, b1, xbuf, n, 1);

  // ---- layer 2 ----
  gemm_att<64><<<gb, 256, 0, stream>>>(xbuf, W2, att_s2, att_d2, hbuf, as_, ad_, n);
  node_agg_kernel<<<nb, 256, 0, stream>>>(ccol, start, cursor, as_, ad_, hbuf, b2, out, n, 0);
}

// Round 7
// 337.350 us; speedup vs baseline: 2.0791x; 1.4246x over previous
//
#include <hip/hip_runtime.h>
#include <cstdint>

// 2-layer GAT, PyG GATConv semantics (concat heads, self-loops, segment softmax).
// R7: CSR build via dst-bucketed counting sort. R6 showed scatter_csr is
// scattered-L2-transaction-bound (~3.4M uncoalesced atomic+write ops, 130us;
// same time as padded R4, and ~same time with 100MB or 7MB of HBM traffic).
// New build: per-block LDS hists (global atomics 1.7M -> 153K), packed u32
// bucket place (1.7M scattered u32 writes, the only remaining scatter), then
// per-bucket LDS counting sort emitting ccol/start/end fully coalesced.
// GEMM (R4) and fused node aggregation (R5) unchanged.
// Softmax max-subtraction omitted: shift-invariant, |e| <= ~10 so exp() safe in f32.

#define CH 4096    // edges per block in hist/place
#define MAXB 512   // LDS bucket array size (NBUCK = ceil(n/256) = 391)
#define SCAP 6144  // pass-2 LDS sort capacity (mean 4352, sigma ~66 -> never hit)

__device__ __forceinline__ float lrelu(float v) { return fmaxf(v, 0.2f * v); }

__global__ void ifill_kernel(int* __restrict__ p, int v, int n) {
  int i = blockIdx.x * blockDim.x + threadIdx.x;
  if (i < n) p[i] = v;
}

// k1: per-block LDS histogram of dst buckets -> global bucket_cnt.
__global__ __launch_bounds__(256) void bucket_hist(const int* __restrict__ edst,
                                                   int E, int nbuck,
                                                   int* __restrict__ bucket_cnt) {
  __shared__ int hist[MAXB];
  const int t = threadIdx.x;
  for (int j = t; j < MAXB; j += 256) hist[j] = 0;
  __syncthreads();
  const int base = blockIdx.x * CH;
#pragma unroll
  for (int k = 0; k < CH / 256; ++k) {
    int e = base + k * 256 + t;
    if (e < E) atomicAdd(&hist[edst[e] >> 8], 1);
  }
  __syncthreads();
  for (int j = t; j < nbuck; j += 256) {
    int c = hist[j];
    if (c) atomicAdd(&bucket_cnt[j], c);
  }
}

// k2: single-WG exclusive scan of bucket_cnt[0..nbuck) -> bucket_base[0..nbuck]
// (base[nbuck] = E) and bucket_cursor copy.
__global__ __launch_bounds__(512) void bucket_scan(const int* __restrict__ bucket_cnt,
                                                   int* __restrict__ bucket_base,
                                                   int* __restrict__ bucket_cursor,
                                                   int nbuck) {
  __shared__ int part[512];
  const int t = threadIdx.x;
  int v = (t < nbuck) ? bucket_cnt[t] : 0;
  part[t] = v;
  __syncthreads();
  for (int off = 1; off < 512; off <<= 1) {
    int u = (t >= off) ? part[t - off] : 0;
    __syncthreads();
    part[t] += u;
    __syncthreads();
  }
  int ex = part[t] - v;  // exclusive
  if (t <= nbuck) {      // t==nbuck writes total E
    int w = (t < nbuck) ? ex : part[nbuck - 1];
    bucket_base[t] = w;
    if (t < nbuck) bucket_cursor[t] = w;
  }
}

// k3: place packed edges into bucket regions. Per-block LDS hist -> one global
// reservation per (block,bucket) -> per-edge LDS rank -> scattered u32 write.
__global__ __launch_bounds__(256) void place_kernel(const int* __restrict__ esrc,
                                                    const int* __restrict__ edst,
                                                    int E, int nbuck,
                                                    int* __restrict__ bucket_cursor,
                                                    unsigned int* __restrict__ pairs) {
  __shared__ int hist[MAXB];
  __shared__ int gbase[MAXB];
  __shared__ int rcnt[MAXB];
  const int t = threadIdx.x;
  for (int j = t; j < MAXB; j += 256) { hist[j] = 0; rcnt[j] = 0; }
  __syncthreads();
  const int base = blockIdx.x * CH;
  int b_[CH / 256];
  unsigned int p_[CH / 256];
#pragma unroll
  for (int k = 0; k < CH / 256; ++k) {
    int e = base + k * 256 + t;
    if (e < E) {
      int d = edst[e];
      int s = esrc[e];
      b_[k] = d >> 8;
      p_[k] = ((unsigned int)s << 8) | (unsigned int)(d & 255);
      atomicAdd(&hist[b_[k]], 1);
    } else {
      b_[k] = -1;
    }
  }
  __syncthreads();
  for (int j = t; j < nbuck; j += 256) {
    int c = hist[j];
    gbase[j] = c ? atomicAdd(&bucket_cursor[j], c) : 0;
  }
  __syncthreads();
#pragma unroll
  for (int k = 0; k < CH / 256; ++k) {
    if (b_[k] >= 0) {
      int r = atomicAdd(&rcnt[b_[k]], 1);
      pairs[gbase[b_[k]] + r] = p_[k];
    }
  }
}

// k4: one block per bucket. LDS counting-sort the bucket's edges by local dst,
// inject self-loops (slot 0 of each dst), emit ccol segment + start/end coalesced.
__global__ __launch_bounds__(256) void bucket_build(
    const unsigned int* __restrict__ pairs, const int* __restrict__ bucket_base,
    int* __restrict__ ccol, int* __restrict__ start, int* __restrict__ endp,
    int n) {
  __shared__ int cnt[256];
  __shared__ int ls[256];
  __shared__ int csave[256];
  __shared__ int part[256];
  __shared__ int sorted[SCAP];
  const int t = threadIdx.x;
  const int b = blockIdx.x;
  const int d0 = b << 8;
  const int DR = min(256, n - d0);
  const int in_base = bucket_base[b];
  const int nloc = bucket_base[b + 1] - in_base;
  const int out_base = in_base + d0;  // self-loops of earlier (full) buckets = d0

  cnt[t] = (t < DR) ? 1 : 0;  // 1 = self-loop
  __syncthreads();
  for (int i = t; i < nloc; i += 256)
    atomicAdd(&cnt[pairs[in_base + i] & 255u], 1);
  __syncthreads();
  int c = cnt[t];
  csave[t] = c;
  part[t] = c;
  __syncthreads();
#pragma unroll
  for (int off = 1; off < 256; off <<= 1) {
    int u = (t >= off) ? part[t - off] : 0;
    __syncthreads();
    part[t] += u;
    __syncthreads();
  }
  ls[t] = part[t] - c;  // exclusive local start
  __syncthreads();
  if (t < DR) {
    int s = out_base + ls[t];
    start[d0 + t] = s;
    endp[d0 + t] = s + csave[t];
    sorted[ls[t]] = d0 + t;  // self-loop src
    cnt[t] = 1;              // reuse as rank counter, slot 0 taken
  }
  __syncthreads();
  for (int i = t; i < nloc; i += 256) {
    unsigned int p = pairs[in_base + i];
    int j = (int)(p & 255u);
    int r = atomicAdd(&cnt[j], 1);
    int pos = ls[j] + r;
    if (pos < SCAP) sorted[pos] = (int)(p >> 8);
  }
  __syncthreads();
  int tot = nloc + DR;
  if (tot > SCAP) tot = SCAP;
  for (int i = t; i < tot; i += 256) ccol[out_base + i] = sorted[i];
}

// h[n][64] = x[n][K] @ W[K][64]; a_s[n][h] = sum_c h*att_src, a_d likewise.
// Tiled GEMM: block = 64 rows x 64 cols, BK=64 chunks staged in LDS.
template <int K>
__global__ __launch_bounds__(256) void gemm_att(
    const float* __restrict__ x, const float* __restrict__ W,
    const float* __restrict__ att_src, const float* __restrict__ att_dst,
    float* __restrict__ h, float* __restrict__ as_, float* __restrict__ ad_,
    int n) {
  __shared__ float xs[64 * 68];  // x tile [row][k], stride 68
  __shared__ float ws[64 * 64];  // W chunk [k][col]
  const int tid = threadIdx.x;
  const int ty = tid >> 4;
  const int tx = tid & 15;
  const int row0 = blockIdx.x * 64;
  const int sr = tid >> 4;
  const int sc = tid & 15;

  float acc[4][4] = {{0.f}};

  for (int c = 0; c < K; c += 64) {
    __syncthreads();
    {  // stage W chunk: linear float4 copy
      const float4* wsrc = (const float4*)(W + (long long)c * 64);
      float4* wdst = (float4*)ws;
#pragma unroll
      for (int j = 0; j < 4; ++j) wdst[tid + j * 256] = wsrc[tid + j * 256];
    }
#pragma unroll
    for (int j = 0; j < 4; ++j) {  // stage x tile (clamped tail rows)
      int r = sr + j * 16;
      int rr = row0 + r;
      if (rr > n - 1) rr = n - 1;
      float4 v = *(const float4*)(x + (long long)rr * K + c + sc * 4);
      *(float4*)(xs + r * 68 + sc * 4) = v;
    }
    __syncthreads();
#pragma unroll 2
    for (int kk = 0; kk < 64; kk += 4) {
      float4 xv[4], wv[4];
#pragma unroll
      for (int i = 0; i < 4; ++i)
        xv[i] = *(const float4*)(xs + (ty * 4 + i) * 68 + kk);
#pragma unroll
      for (int q = 0; q < 4; ++q)
        wv[q] = *(const float4*)(ws + (kk + q) * 64 + tx * 4);
#pragma unroll
      for (int q = 0; q < 4; ++q) {
#pragma unroll
        for (int i = 0; i < 4; ++i) {
          float xq = (q == 0) ? xv[i].x : (q == 1) ? xv[i].y : (q == 2) ? xv[i].z : xv[i].w;
          acc[i][0] = fmaf(xq, wv[q].x, acc[i][0]);
          acc[i][1] = fmaf(xq, wv[q].y, acc[i][1]);
          acc[i][2] = fmaf(xq, wv[q].z, acc[i][2]);
          acc[i][3] = fmaf(xq, wv[q].w, acc[i][3]);
        }
      }
    }
  }

  // Epilogue: h store + per-head att dots (reduce over 4 lanes sharing a head).
  const float4 atts = *(const float4*)(att_src + tx * 4);
  const float4 attd = *(const float4*)(att_dst + tx * 4);
  const int head = tx >> 2;
#pragma unroll
  for (int i = 0; i < 4; ++i) {
    int row = row0 + ty * 4 + i;
    if (row >= n) break;
    float4 hv = make_float4(acc[i][0], acc[i][1], acc[i][2], acc[i][3]);
    *(float4*)(h + (long long)row * 64 + tx * 4) = hv;
    float s = acc[i][0] * atts.x + acc[i][1] * atts.y + acc[i][2] * atts.z + acc[i][3] * atts.w;
    float d = acc[i][0] * attd.x + acc[i][1] * attd.y + acc[i][2] * attd.z + acc[i][3] * attd.w;
    s += __shfl_xor(s, 1);
    s += __shfl_xor(s, 2);
    d += __shfl_xor(d, 1);
    d += __shfl_xor(d, 2);
    if ((tx & 3) == 0) {
      as_[(long long)row * 4 + head] = s;
      ad_[(long long)row * 4 + head] = d;
    }
  }
}

// One wave per dst node; lane = channel. Single pass accumulates
// num = sum p*h[src] and den = sum p in registers, then out = num/den + b (+relu).
__global__ __launch_bounds__(256) void node_agg_kernel(
    const int* __restrict__ ccol, const int* __restrict__ start,
    const int* __restrict__ endp,
    const float* __restrict__ as_, const float* __restrict__ ad_,
    const float* __restrict__ h, const float* __restrict__ bias,
    float* __restrict__ out, int n, int do_relu) {
  int node = blockIdx.x * 4 + (threadIdx.x >> 6);
  if (node >= n) return;
  const int lane = threadIdx.x & 63;
  const int hh = lane >> 4;
  const float adv = ad_[(long long)node * 4 + hh];
  const int s0i = start[node];
  const int e0i = endp[node];
  const int d = e0i - s0i;
  const int* cp = ccol + s0i;
  float acc = 0.f, den = 0.f;
  int i = 0;
  for (; i + 2 <= d; i += 2) {  // 2x unroll for load ILP
    int s0 = cp[i], s1 = cp[i + 1];
    float p0 = __expf(lrelu(as_[(long long)s0 * 4 + hh] + adv));
    float p1 = __expf(lrelu(as_[(long long)s1 * 4 + hh] + adv));
    float h0 = h[(long long)s0 * 64 + lane];
    float h1 = h[(long long)s1 * 64 + lane];
    den += p0 + p1;
    acc = fmaf(p0, h0, acc);
    acc = fmaf(p1, h1, acc);
  }
  if (i < d) {
    int s0 = cp[i];
    float p0 = __expf(lrelu(as_[(long long)s0 * 4 + hh] + adv));
    den += p0;
    acc = fmaf(p0, h[(long long)s0 * 64 + lane], acc);
  }
  float v = acc / (den + 1e-16f) + bias[lane];
  out[(long long)node * 64 + lane] = do_relu ? fmaxf(v, 0.f) : v;
}

extern "C" void kernel_launch(void* const* d_in, const int* in_sizes, int n_in,
                              void* d_out, int out_size, void* d_ws, size_t ws_size,
                              hipStream_t stream) {
  const float* x = (const float*)d_in[0];
  const int* ei = (const int*)d_in[1];
  const float* W1 = (const float*)d_in[2];
  const float* att_s1 = (const float*)d_in[3];
  const float* att_d1 = (const float*)d_in[4];
  const float* b1 = (const float*)d_in[5];
  const float* W2 = (const float*)d_in[6];
  const float* att_s2 = (const float*)d_in[7];
  const float* att_d2 = (const float*)d_in[8];
  const float* b2 = (const float*)d_in[9];

  const int n = in_sizes[0] / 256;  // 100000
  const int E = in_sizes[1] / 2;    // 1600000
  const int* esrc = ei;
  const int* edst = ei + E;
  const int nbuck = (n + 255) >> 8;  // 391

  float* wsf = (float*)d_ws;
  float* hbuf = wsf;                            // [n*64]
  float* xbuf = hbuf + (long long)n * 64;       // [n*64]
  float* as_ = xbuf + (long long)n * 64;        // [n*4]
  float* ad_ = as_ + (long long)n * 4;          // [n*4]
  int* bucket_cnt = (int*)(ad_ + (long long)n * 4);  // [MAXB]
  int* bucket_base = bucket_cnt + MAXB;         // [MAXB+1]
  int* bucket_cursor = bucket_base + MAXB + 1;  // [MAXB]
  int* start = bucket_cursor + MAXB;            // [n]
  int* endp = start + n;                        // [n]
  unsigned int* pairs = (unsigned int*)(endp + n);  // [E]
  int* ccol = (int*)(pairs + E);                // [E+n]
  float* out = (float*)d_out;

  const int ebk = (E + CH - 1) / CH;  // 391 edge-chunk blocks
  const int gb = (n + 63) / 64;
  const int nb = (n + 3) / 4;

  // ---- CSR bucket build (shared by both layers) ----
  ifill_kernel<<<(MAXB + 255) / 256, 256, 0, stream>>>(bucket_cnt, 0, MAXB);
  bucket_hist<<<ebk, 256, 0, stream>>>(edst, E, nbuck, bucket_cnt);
  bucket_scan<<<1, 512, 0, stream>>>(bucket_cnt, bucket_base, bucket_cursor, nbuck);
  place_kernel<<<ebk, 256, 0, stream>>>(esrc, edst, E, nbuck, bucket_cursor, pairs);
  bucket_build<<<nbuck, 256, 0, stream>>>(pairs, bucket_base, ccol, start, endp, n);

  // ---- layer 1 ----
  gemm_att<256><<<gb, 256, 0, stream>>>(x, W1, att_s1, att_d1, hbuf, as_, ad_, n);
  node_agg_kernel<<<nb, 256, 0, stream>>>(ccol, start, endp, as_, ad_, hbuf, b1, xbuf, n, 1);

  // ---- layer 2 ----
  gemm_att<64><<<gb, 256, 0, stream>>>(xbuf, W2, att_s2, att_d2, hbuf, as_, ad_, n);
  node_agg_kernel<<<nb, 256, 0, stream>>>(ccol, start, endp, as_, ad_, hbuf, b2, out, n, 0);
}

// Round 8
// 270.207 us; speedup vs baseline: 2.5957x; 1.2485x over previous
//
#include <hip/hip_runtime.h>
#include <hip/hip_fp16.h>
#include <cstdint>

// 2-layer GAT, PyG GATConv semantics (concat heads, self-loops, segment softmax).
// R8: h gather table stored as fp16 (node_agg is gather-BW-bound: 240MB FETCH
// per dispatch on the random 256B/edge h[src] gather; fp16 halves table and
// miss bytes). Softmax math stays f32. 4x unrolled agg loop for MLP.
// CSR bucketed build (R7), LDS-tiled GEMM (R4) otherwise unchanged.
// Softmax max-subtraction omitted: shift-invariant, |e| <= ~10 so exp() safe in f32.

#define CH 4096    // edges per block in hist/place
#define MAXB 512   // LDS bucket array size (NBUCK = ceil(n/256) = 391)
#define SCAP 6144  // pass-2 LDS sort capacity (mean 4352, sigma ~66 -> never hit)

__device__ __forceinline__ float lrelu(float v) { return fmaxf(v, 0.2f * v); }

__global__ void ifill_kernel(int* __restrict__ p, int v, int n) {
  int i = blockIdx.x * blockDim.x + threadIdx.x;
  if (i < n) p[i] = v;
}

// k1: per-block LDS histogram of dst buckets -> global bucket_cnt.
__global__ __launch_bounds__(256) void bucket_hist(const int* __restrict__ edst,
                                                   int E, int nbuck,
                                                   int* __restrict__ bucket_cnt) {
  __shared__ int hist[MAXB];
  const int t = threadIdx.x;
  for (int j = t; j < MAXB; j += 256) hist[j] = 0;
  __syncthreads();
  const int base = blockIdx.x * CH;
#pragma unroll
  for (int k = 0; k < CH / 256; ++k) {
    int e = base + k * 256 + t;
    if (e < E) atomicAdd(&hist[edst[e] >> 8], 1);
  }
  __syncthreads();
  for (int j = t; j < nbuck; j += 256) {
    int c = hist[j];
    if (c) atomicAdd(&bucket_cnt[j], c);
  }
}

// k2: single-WG exclusive scan of bucket_cnt[0..nbuck) -> bucket_base[0..nbuck]
// (base[nbuck] = E) and bucket_cursor copy.
__global__ __launch_bounds__(512) void bucket_scan(const int* __restrict__ bucket_cnt,
                                                   int* __restrict__ bucket_base,
                                                   int* __restrict__ bucket_cursor,
                                                   int nbuck) {
  __shared__ int part[512];
  const int t = threadIdx.x;
  int v = (t < nbuck) ? bucket_cnt[t] : 0;
  part[t] = v;
  __syncthreads();
  for (int off = 1; off < 512; off <<= 1) {
    int u = (t >= off) ? part[t - off] : 0;
    __syncthreads();
    part[t] += u;
    __syncthreads();
  }
  int ex = part[t] - v;  // exclusive
  if (t <= nbuck) {      // t==nbuck writes total E
    int w = (t < nbuck) ? ex : part[nbuck - 1];
    bucket_base[t] = w;
    if (t < nbuck) bucket_cursor[t] = w;
  }
}

// k3: place packed edges into bucket regions. Per-block LDS hist -> one global
// reservation per (block,bucket) -> per-edge LDS rank -> scattered u32 write.
__global__ __launch_bounds__(256) void place_kernel(const int* __restrict__ esrc,
                                                    const int* __restrict__ edst,
                                                    int E, int nbuck,
                                                    int* __restrict__ bucket_cursor,
                                                    unsigned int* __restrict__ pairs) {
  __shared__ int hist[MAXB];
  __shared__ int gbase[MAXB];
  __shared__ int rcnt[MAXB];
  const int t = threadIdx.x;
  for (int j = t; j < MAXB; j += 256) { hist[j] = 0; rcnt[j] = 0; }
  __syncthreads();
  const int base = blockIdx.x * CH;
  int b_[CH / 256];
  unsigned int p_[CH / 256];
#pragma unroll
  for (int k = 0; k < CH / 256; ++k) {
    int e = base + k * 256 + t;
    if (e < E) {
      int d = edst[e];
      int s = esrc[e];
      b_[k] = d >> 8;
      p_[k] = ((unsigned int)s << 8) | (unsigned int)(d & 255);
      atomicAdd(&hist[b_[k]], 1);
    } else {
      b_[k] = -1;
    }
  }
  __syncthreads();
  for (int j = t; j < nbuck; j += 256) {
    int c = hist[j];
    gbase[j] = c ? atomicAdd(&bucket_cursor[j], c) : 0;
  }
  __syncthreads();
#pragma unroll
  for (int k = 0; k < CH / 256; ++k) {
    if (b_[k] >= 0) {
      int r = atomicAdd(&rcnt[b_[k]], 1);
      pairs[gbase[b_[k]] + r] = p_[k];
    }
  }
}

// k4: one block per bucket. LDS counting-sort the bucket's edges by local dst,
// inject self-loops (slot 0 of each dst), emit ccol segment + start/end coalesced.
__global__ __launch_bounds__(256) void bucket_build(
    const unsigned int* __restrict__ pairs, const int* __restrict__ bucket_base,
    int* __restrict__ ccol, int* __restrict__ start, int* __restrict__ endp,
    int n) {
  __shared__ int cnt[256];
  __shared__ int ls[256];
  __shared__ int csave[256];
  __shared__ int part[256];
  __shared__ int sorted[SCAP];
  const int t = threadIdx.x;
  const int b = blockIdx.x;
  const int d0 = b << 8;
  const int DR = min(256, n - d0);
  const int in_base = bucket_base[b];
  const int nloc = bucket_base[b + 1] - in_base;
  const int out_base = in_base + d0;  // self-loops of earlier (full) buckets = d0

  cnt[t] = (t < DR) ? 1 : 0;  // 1 = self-loop
  __syncthreads();
  for (int i = t; i < nloc; i += 256)
    atomicAdd(&cnt[pairs[in_base + i] & 255u], 1);
  __syncthreads();
  int c = cnt[t];
  csave[t] = c;
  part[t] = c;
  __syncthreads();
#pragma unroll
  for (int off = 1; off < 256; off <<= 1) {
    int u = (t >= off) ? part[t - off] : 0;
    __syncthreads();
    part[t] += u;
    __syncthreads();
  }
  ls[t] = part[t] - c;  // exclusive local start
  __syncthreads();
  if (t < DR) {
    int s = out_base + ls[t];
    start[d0 + t] = s;
    endp[d0 + t] = s + csave[t];
    sorted[ls[t]] = d0 + t;  // self-loop src
    cnt[t] = 1;              // reuse as rank counter, slot 0 taken
  }
  __syncthreads();
  for (int i = t; i < nloc; i += 256) {
    unsigned int p = pairs[in_base + i];
    int j = (int)(p & 255u);
    int r = atomicAdd(&cnt[j], 1);
    int pos = ls[j] + r;
    if (pos < SCAP) sorted[pos] = (int)(p >> 8);
  }
  __syncthreads();
  int tot = nloc + DR;
  if (tot > SCAP) tot = SCAP;
  for (int i = t; i < tot; i += 256) ccol[out_base + i] = sorted[i];
}

// h[n][64] = x[n][K] @ W[K][64] (h stored fp16); a_s/a_d = per-head att dots.
// Tiled GEMM: block = 64 rows x 64 cols, BK=64 chunks staged in LDS.
template <int K>
__global__ __launch_bounds__(256) void gemm_att(
    const float* __restrict__ x, const float* __restrict__ W,
    const float* __restrict__ att_src, const float* __restrict__ att_dst,
    __half* __restrict__ h, float* __restrict__ as_, float* __restrict__ ad_,
    int n) {
  __shared__ float xs[64 * 68];  // x tile [row][k], stride 68
  __shared__ float ws[64 * 64];  // W chunk [k][col]
  const int tid = threadIdx.x;
  const int ty = tid >> 4;
  const int tx = tid & 15;
  const int row0 = blockIdx.x * 64;
  const int sr = tid >> 4;
  const int sc = tid & 15;

  float acc[4][4] = {{0.f}};

  for (int c = 0; c < K; c += 64) {
    __syncthreads();
    {  // stage W chunk: linear float4 copy
      const float4* wsrc = (const float4*)(W + (long long)c * 64);
      float4* wdst = (float4*)ws;
#pragma unroll
      for (int j = 0; j < 4; ++j) wdst[tid + j * 256] = wsrc[tid + j * 256];
    }
#pragma unroll
    for (int j = 0; j < 4; ++j) {  // stage x tile (clamped tail rows)
      int r = sr + j * 16;
      int rr = row0 + r;
      if (rr > n - 1) rr = n - 1;
      float4 v = *(const float4*)(x + (long long)rr * K + c + sc * 4);
      *(float4*)(xs + r * 68 + sc * 4) = v;
    }
    __syncthreads();
#pragma unroll 2
    for (int kk = 0; kk < 64; kk += 4) {
      float4 xv[4], wv[4];
#pragma unroll
      for (int i = 0; i < 4; ++i)
        xv[i] = *(const float4*)(xs + (ty * 4 + i) * 68 + kk);
#pragma unroll
      for (int q = 0; q < 4; ++q)
        wv[q] = *(const float4*)(ws + (kk + q) * 64 + tx * 4);
#pragma unroll
      for (int q = 0; q < 4; ++q) {
#pragma unroll
        for (int i = 0; i < 4; ++i) {
          float xq = (q == 0) ? xv[i].x : (q == 1) ? xv[i].y : (q == 2) ? xv[i].z : xv[i].w;
          acc[i][0] = fmaf(xq, wv[q].x, acc[i][0]);
          acc[i][1] = fmaf(xq, wv[q].y, acc[i][1]);
          acc[i][2] = fmaf(xq, wv[q].z, acc[i][2]);
          acc[i][3] = fmaf(xq, wv[q].w, acc[i][3]);
        }
      }
    }
  }

  // Epilogue: fp16 h store + per-head att dots (f32; reduce over 4 lanes/head).
  const float4 atts = *(const float4*)(att_src + tx * 4);
  const float4 attd = *(const float4*)(att_dst + tx * 4);
  const int head = tx >> 2;
#pragma unroll
  for (int i = 0; i < 4; ++i) {
    int row = row0 + ty * 4 + i;
    if (row >= n) break;
    ushort4 hv;
    hv.x = __half_as_ushort(__float2half_rn(acc[i][0]));
    hv.y = __half_as_ushort(__float2half_rn(acc[i][1]));
    hv.z = __half_as_ushort(__float2half_rn(acc[i][2]));
    hv.w = __half_as_ushort(__float2half_rn(acc[i][3]));
    *(ushort4*)(h + (long long)row * 64 + tx * 4) = hv;
    float s = acc[i][0] * atts.x + acc[i][1] * atts.y + acc[i][2] * atts.z + acc[i][3] * atts.w;
    float d = acc[i][0] * attd.x + acc[i][1] * attd.y + acc[i][2] * attd.z + acc[i][3] * attd.w;
    s += __shfl_xor(s, 1);
    s += __shfl_xor(s, 2);
    d += __shfl_xor(d, 1);
    d += __shfl_xor(d, 2);
    if ((tx & 3) == 0) {
      as_[(long long)row * 4 + head] = s;
      ad_[(long long)row * 4 + head] = d;
    }
  }
}

// One wave per dst node; lane = channel. Single pass accumulates
// num = sum p*h[src] (h fp16) and den = sum p, then out = num/den + b (+relu).
__global__ __launch_bounds__(256) void node_agg_kernel(
    const int* __restrict__ ccol, const int* __restrict__ start,
    const int* __restrict__ endp,
    const float* __restrict__ as_, const float* __restrict__ ad_,
    const __half* __restrict__ h, const float* __restrict__ bias,
    float* __restrict__ out, int n, int do_relu) {
  int node = blockIdx.x * 4 + (threadIdx.x >> 6);
  if (node >= n) return;
  const int lane = threadIdx.x & 63;
  const int hh = lane >> 4;
  const float adv = ad_[(long long)node * 4 + hh];
  const int s0i = start[node];
  const int e0i = endp[node];
  const int d = e0i - s0i;
  const int* cp = ccol + s0i;
  float acc = 0.f, den = 0.f;
  int i = 0;
  for (; i + 4 <= d; i += 4) {  // 4x unroll for memory-level parallelism
    int s0 = cp[i], s1 = cp[i + 1], s2 = cp[i + 2], s3 = cp[i + 3];
    float p0 = __expf(lrelu(as_[(long long)s0 * 4 + hh] + adv));
    float p1 = __expf(lrelu(as_[(long long)s1 * 4 + hh] + adv));
    float p2 = __expf(lrelu(as_[(long long)s2 * 4 + hh] + adv));
    float p3 = __expf(lrelu(as_[(long long)s3 * 4 + hh] + adv));
    float h0 = __half2float(h[(long long)s0 * 64 + lane]);
    float h1 = __half2float(h[(long long)s1 * 64 + lane]);
    float h2 = __half2float(h[(long long)s2 * 64 + lane]);
    float h3 = __half2float(h[(long long)s3 * 64 + lane]);
    den += (p0 + p1) + (p2 + p3);
    acc = fmaf(p0, h0, acc);
    acc = fmaf(p1, h1, acc);
    acc = fmaf(p2, h2, acc);
    acc = fmaf(p3, h3, acc);
  }
  for (; i < d; ++i) {
    int s0 = cp[i];
    float p0 = __expf(lrelu(as_[(long long)s0 * 4 + hh] + adv));
    den += p0;
    acc = fmaf(p0, __half2float(h[(long long)s0 * 64 + lane]), acc);
  }
  float v = acc / (den + 1e-16f) + bias[lane];
  out[(long long)node * 64 + lane] = do_relu ? fmaxf(v, 0.f) : v;
}

extern "C" void kernel_launch(void* const* d_in, const int* in_sizes, int n_in,
                              void* d_out, int out_size, void* d_ws, size_t ws_size,
                              hipStream_t stream) {
  const float* x = (const float*)d_in[0];
  const int* ei = (const int*)d_in[1];
  const float* W1 = (const float*)d_in[2];
  const float* att_s1 = (const float*)d_in[3];
  const float* att_d1 = (const float*)d_in[4];
  const float* b1 = (const float*)d_in[5];
  const float* W2 = (const float*)d_in[6];
  const float* att_s2 = (const float*)d_in[7];
  const float* att_d2 = (const float*)d_in[8];
  const float* b2 = (const float*)d_in[9];

  const int n = in_sizes[0] / 256;  // 100000
  const int E = in_sizes[1] / 2;    // 1600000
  const int* esrc = ei;
  const int* edst = ei + E;
  const int nbuck = (n + 255) >> 8;  // 391

  float* wsf = (float*)d_ws;
  __half* hbuf = (__half*)wsf;                  // [n*64] fp16 (region sized n*64 floats)
  float* xbuf = wsf + (long long)n * 64;        // [n*64] f32 layer-1 out / layer-2 in
  float* as_ = xbuf + (long long)n * 64;        // [n*4]
  float* ad_ = as_ + (long long)n * 4;          // [n*4]
  int* bucket_cnt = (int*)(ad_ + (long long)n * 4);  // [MAXB]
  int* bucket_base = bucket_cnt + MAXB;         // [MAXB+1]
  int* bucket_cursor = bucket_base + MAXB + 1;  // [MAXB]
  int* start = bucket_cursor + MAXB;            // [n]
  int* endp = start + n;                        // [n]
  unsigned int* pairs = (unsigned int*)(endp + n);  // [E]
  int* ccol = (int*)(pairs + E);                // [E+n]
  float* out = (float*)d_out;

  const int ebk = (E + CH - 1) / CH;  // 391 edge-chunk blocks
  const int gb = (n + 63) / 64;
  const int nb = (n + 3) / 4;

  // ---- CSR bucket build (shared by both layers) ----
  ifill_kernel<<<(MAXB + 255) / 256, 256, 0, stream>>>(bucket_cnt, 0, MAXB);
  bucket_hist<<<ebk, 256, 0, stream>>>(edst, E, nbuck, bucket_cnt);
  bucket_scan<<<1, 512, 0, stream>>>(bucket_cnt, bucket_base, bucket_cursor, nbuck);
  place_kernel<<<ebk, 256, 0, stream>>>(esrc, edst, E, nbuck, bucket_cursor, pairs);
  bucket_build<<<nbuck, 256, 0, stream>>>(pairs, bucket_base, ccol, start, endp, n);

  // ---- layer 1 ----
  gemm_att<256><<<gb, 256, 0, stream>>>(x, W1, att_s1, att_d1, hbuf, as_, ad_, n);
  node_agg_kernel<<<nb, 256, 0, stream>>>(ccol, start, endp, as_, ad_, hbuf, b1, xbuf, n, 1);

  // ---- layer 2 ----
  gemm_att<64><<<gb, 256, 0, stream>>>(xbuf, W2, att_s2, att_d2, hbuf, as_, ad_, n);
  node_agg_kernel<<<nb, 256, 0, stream>>>(ccol, start, endp, as_, ad_, hbuf, b2, out, n, 0);
}

// Round 9
// 227.294 us; speedup vs baseline: 3.0858x; 1.1888x over previous
//
#include <hip/hip_runtime.h>
#include <hip/hip_fp16.h>
#include <cstdint>

// 2-layer GAT, PyG GATConv semantics (concat heads, self-loops, segment softmax).
// R9: node_agg channel-paired (__half2, 32 lanes/edge, 2 nodes/wave) to halve
// per-edge VALU+load instruction count (R8 showed VALUBusy ~60%: instruction-
// issue-bound, not purely fetch-bound). 32-bit indexing throughout node_agg.
// fp16 h table (R8), CSR bucketed build (R7), LDS-tiled GEMM (R4) unchanged.
// Softmax max-subtraction omitted: shift-invariant, |e| <= ~10 so exp() safe in f32.

#define CH 4096    // edges per block in hist/place
#define MAXB 512   // LDS bucket array size (NBUCK = ceil(n/256) = 391)
#define SCAP 6144  // pass-2 LDS sort capacity (mean 4352, sigma ~66 -> never hit)

__device__ __forceinline__ float lrelu(float v) { return fmaxf(v, 0.2f * v); }

__global__ void ifill_kernel(int* __restrict__ p, int v, int n) {
  int i = blockIdx.x * blockDim.x + threadIdx.x;
  if (i < n) p[i] = v;
}

// k1: per-block LDS histogram of dst buckets -> global bucket_cnt.
__global__ __launch_bounds__(256) void bucket_hist(const int* __restrict__ edst,
                                                   int E, int nbuck,
                                                   int* __restrict__ bucket_cnt) {
  __shared__ int hist[MAXB];
  const int t = threadIdx.x;
  for (int j = t; j < MAXB; j += 256) hist[j] = 0;
  __syncthreads();
  const int base = blockIdx.x * CH;
#pragma unroll
  for (int k = 0; k < CH / 256; ++k) {
    int e = base + k * 256 + t;
    if (e < E) atomicAdd(&hist[edst[e] >> 8], 1);
  }
  __syncthreads();
  for (int j = t; j < nbuck; j += 256) {
    int c = hist[j];
    if (c) atomicAdd(&bucket_cnt[j], c);
  }
}

// k2: single-WG exclusive scan of bucket_cnt[0..nbuck) -> bucket_base[0..nbuck]
// (base[nbuck] = E) and bucket_cursor copy.
__global__ __launch_bounds__(512) void bucket_scan(const int* __restrict__ bucket_cnt,
                                                   int* __restrict__ bucket_base,
                                                   int* __restrict__ bucket_cursor,
                                                   int nbuck) {
  __shared__ int part[512];
  const int t = threadIdx.x;
  int v = (t < nbuck) ? bucket_cnt[t] : 0;
  part[t] = v;
  __syncthreads();
  for (int off = 1; off < 512; off <<= 1) {
    int u = (t >= off) ? part[t - off] : 0;
    __syncthreads();
    part[t] += u;
    __syncthreads();
  }
  int ex = part[t] - v;  // exclusive
  if (t <= nbuck) {      // t==nbuck writes total E
    int w = (t < nbuck) ? ex : part[nbuck - 1];
    bucket_base[t] = w;
    if (t < nbuck) bucket_cursor[t] = w;
  }
}

// k3: place packed edges into bucket regions. Per-block LDS hist -> one global
// reservation per (block,bucket) -> per-edge LDS rank -> scattered u32 write.
__global__ __launch_bounds__(256) void place_kernel(const int* __restrict__ esrc,
                                                    const int* __restrict__ edst,
                                                    int E, int nbuck,
                                                    int* __restrict__ bucket_cursor,
                                                    unsigned int* __restrict__ pairs) {
  __shared__ int hist[MAXB];
  __shared__ int gbase[MAXB];
  __shared__ int rcnt[MAXB];
  const int t = threadIdx.x;
  for (int j = t; j < MAXB; j += 256) { hist[j] = 0; rcnt[j] = 0; }
  __syncthreads();
  const int base = blockIdx.x * CH;
  int b_[CH / 256];
  unsigned int p_[CH / 256];
#pragma unroll
  for (int k = 0; k < CH / 256; ++k) {
    int e = base + k * 256 + t;
    if (e < E) {
      int d = edst[e];
      int s = esrc[e];
      b_[k] = d >> 8;
      p_[k] = ((unsigned int)s << 8) | (unsigned int)(d & 255);
      atomicAdd(&hist[b_[k]], 1);
    } else {
      b_[k] = -1;
    }
  }
  __syncthreads();
  for (int j = t; j < nbuck; j += 256) {
    int c = hist[j];
    gbase[j] = c ? atomicAdd(&bucket_cursor[j], c) : 0;
  }
  __syncthreads();
#pragma unroll
  for (int k = 0; k < CH / 256; ++k) {
    if (b_[k] >= 0) {
      int r = atomicAdd(&rcnt[b_[k]], 1);
      pairs[gbase[b_[k]] + r] = p_[k];
    }
  }
}

// k4: one block per bucket. LDS counting-sort the bucket's edges by local dst,
// inject self-loops (slot 0 of each dst), emit ccol segment + start/end coalesced.
__global__ __launch_bounds__(256) void bucket_build(
    const unsigned int* __restrict__ pairs, const int* __restrict__ bucket_base,
    int* __restrict__ ccol, int* __restrict__ start, int* __restrict__ endp,
    int n) {
  __shared__ int cnt[256];
  __shared__ int ls[256];
  __shared__ int csave[256];
  __shared__ int part[256];
  __shared__ int sorted[SCAP];
  const int t = threadIdx.x;
  const int b = blockIdx.x;
  const int d0 = b << 8;
  const int DR = min(256, n - d0);
  const int in_base = bucket_base[b];
  const int nloc = bucket_base[b + 1] - in_base;
  const int out_base = in_base + d0;  // self-loops of earlier (full) buckets = d0

  cnt[t] = (t < DR) ? 1 : 0;  // 1 = self-loop
  __syncthreads();
  for (int i = t; i < nloc; i += 256)
    atomicAdd(&cnt[pairs[in_base + i] & 255u], 1);
  __syncthreads();
  int c = cnt[t];
  csave[t] = c;
  part[t] = c;
  __syncthreads();
#pragma unroll
  for (int off = 1; off < 256; off <<= 1) {
    int u = (t >= off) ? part[t - off] : 0;
    __syncthreads();
    part[t] += u;
    __syncthreads();
  }
  ls[t] = part[t] - c;  // exclusive local start
  __syncthreads();
  if (t < DR) {
    int s = out_base + ls[t];
    start[d0 + t] = s;
    endp[d0 + t] = s + csave[t];
    sorted[ls[t]] = d0 + t;  // self-loop src
    cnt[t] = 1;              // reuse as rank counter, slot 0 taken
  }
  __syncthreads();
  for (int i = t; i < nloc; i += 256) {
    unsigned int p = pairs[in_base + i];
    int j = (int)(p & 255u);
    int r = atomicAdd(&cnt[j], 1);
    int pos = ls[j] + r;
    if (pos < SCAP) sorted[pos] = (int)(p >> 8);
  }
  __syncthreads();
  int tot = nloc + DR;
  if (tot > SCAP) tot = SCAP;
  for (int i = t; i < tot; i += 256) ccol[out_base + i] = sorted[i];
}

// h[n][64] = x[n][K] @ W[K][64] (h stored fp16); a_s/a_d = per-head att dots.
// Tiled GEMM: block = 64 rows x 64 cols, BK=64 chunks staged in LDS.
template <int K>
__global__ __launch_bounds__(256) void gemm_att(
    const float* __restrict__ x, const float* __restrict__ W,
    const float* __restrict__ att_src, const float* __restrict__ att_dst,
    __half* __restrict__ h, float* __restrict__ as_, float* __restrict__ ad_,
    int n) {
  __shared__ float xs[64 * 68];  // x tile [row][k], stride 68
  __shared__ float ws[64 * 64];  // W chunk [k][col]
  const int tid = threadIdx.x;
  const int ty = tid >> 4;
  const int tx = tid & 15;
  const int row0 = blockIdx.x * 64;
  const int sr = tid >> 4;
  const int sc = tid & 15;

  float acc[4][4] = {{0.f}};

  for (int c = 0; c < K; c += 64) {
    __syncthreads();
    {  // stage W chunk: linear float4 copy
      const float4* wsrc = (const float4*)(W + (long long)c * 64);
      float4* wdst = (float4*)ws;
#pragma unroll
      for (int j = 0; j < 4; ++j) wdst[tid + j * 256] = wsrc[tid + j * 256];
    }
#pragma unroll
    for (int j = 0; j < 4; ++j) {  // stage x tile (clamped tail rows)
      int r = sr + j * 16;
      int rr = row0 + r;
      if (rr > n - 1) rr = n - 1;
      float4 v = *(const float4*)(x + (long long)rr * K + c + sc * 4);
      *(float4*)(xs + r * 68 + sc * 4) = v;
    }
    __syncthreads();
#pragma unroll 2
    for (int kk = 0; kk < 64; kk += 4) {
      float4 xv[4], wv[4];
#pragma unroll
      for (int i = 0; i < 4; ++i)
        xv[i] = *(const float4*)(xs + (ty * 4 + i) * 68 + kk);
#pragma unroll
      for (int q = 0; q < 4; ++q)
        wv[q] = *(const float4*)(ws + (kk + q) * 64 + tx * 4);
#pragma unroll
      for (int q = 0; q < 4; ++q) {
#pragma unroll
        for (int i = 0; i < 4; ++i) {
          float xq = (q == 0) ? xv[i].x : (q == 1) ? xv[i].y : (q == 2) ? xv[i].z : xv[i].w;
          acc[i][0] = fmaf(xq, wv[q].x, acc[i][0]);
          acc[i][1] = fmaf(xq, wv[q].y, acc[i][1]);
          acc[i][2] = fmaf(xq, wv[q].z, acc[i][2]);
          acc[i][3] = fmaf(xq, wv[q].w, acc[i][3]);
        }
      }
    }
  }

  // Epilogue: fp16 h store + per-head att dots (f32; reduce over 4 lanes/head).
  const float4 atts = *(const float4*)(att_src + tx * 4);
  const float4 attd = *(const float4*)(att_dst + tx * 4);
  const int head = tx >> 2;
#pragma unroll
  for (int i = 0; i < 4; ++i) {
    int row = row0 + ty * 4 + i;
    if (row >= n) break;
    ushort4 hv;
    hv.x = __half_as_ushort(__float2half_rn(acc[i][0]));
    hv.y = __half_as_ushort(__float2half_rn(acc[i][1]));
    hv.z = __half_as_ushort(__float2half_rn(acc[i][2]));
    hv.w = __half_as_ushort(__float2half_rn(acc[i][3]));
    *(ushort4*)(h + (long long)row * 64 + tx * 4) = hv;
    float s = acc[i][0] * atts.x + acc[i][1] * atts.y + acc[i][2] * atts.z + acc[i][3] * atts.w;
    float d = acc[i][0] * attd.x + acc[i][1] * attd.y + acc[i][2] * attd.z + acc[i][3] * attd.w;
    s += __shfl_xor(s, 1);
    s += __shfl_xor(s, 2);
    d += __shfl_xor(d, 1);
    d += __shfl_xor(d, 2);
    if ((tx & 3) == 0) {
      as_[(long long)row * 4 + head] = s;
      ad_[(long long)row * 4 + head] = d;
    }
  }
}

// Half-wave (32 lanes) per dst node, 2 adjacent nodes per wave; lane covers 2
// channels via __half2. num/den accumulate in registers; out = num/den + b (+relu).
// All offsets 32-bit (max 6.4M).
__global__ __launch_bounds__(256) void node_agg_kernel(
    const int* __restrict__ ccol, const int* __restrict__ start,
    const int* __restrict__ endp,
    const float* __restrict__ as_, const float* __restrict__ ad_,
    const __half2* __restrict__ h2, const float* __restrict__ bias,
    float* __restrict__ out, int n, int do_relu) {
  const int node = blockIdx.x * 8 + (threadIdx.x >> 5);
  if (node >= n) return;
  const int hl = threadIdx.x & 31;  // half-lane: channels 2hl, 2hl+1
  const int hh = hl >> 3;           // head (8 lanes/head)
  const float adv = ad_[node * 4 + hh];
  const int s0i = start[node];
  const int d = endp[node] - s0i;
  const int* cp = ccol + s0i;
  float ax = 0.f, ay = 0.f, den = 0.f;
  int i = 0;
  for (; i + 4 <= d; i += 4) {  // 4x unroll for memory-level parallelism
    int s0 = cp[i], s1 = cp[i + 1], s2 = cp[i + 2], s3 = cp[i + 3];
    float p0 = __expf(lrelu(as_[s0 * 4 + hh] + adv));
    float p1 = __expf(lrelu(as_[s1 * 4 + hh] + adv));
    float p2 = __expf(lrelu(as_[s2 * 4 + hh] + adv));
    float p3 = __expf(lrelu(as_[s3 * 4 + hh] + adv));
    float2 h0 = __half22float2(h2[s0 * 32 + hl]);
    float2 h1 = __half22float2(h2[s1 * 32 + hl]);
    float2 h2v = __half22float2(h2[s2 * 32 + hl]);
    float2 h3 = __half22float2(h2[s3 * 32 + hl]);
    den += (p0 + p1) + (p2 + p3);
    ax = fmaf(p0, h0.x, ax); ay = fmaf(p0, h0.y, ay);
    ax = fmaf(p1, h1.x, ax); ay = fmaf(p1, h1.y, ay);
    ax = fmaf(p2, h2v.x, ax); ay = fmaf(p2, h2v.y, ay);
    ax = fmaf(p3, h3.x, ax); ay = fmaf(p3, h3.y, ay);
  }
  for (; i < d; ++i) {
    int s0 = cp[i];
    float p0 = __expf(lrelu(as_[s0 * 4 + hh] + adv));
    float2 h0 = __half22float2(h2[s0 * 32 + hl]);
    den += p0;
    ax = fmaf(p0, h0.x, ax); ay = fmaf(p0, h0.y, ay);
  }
  const float inv = 1.0f / (den + 1e-16f);
  float vx = ax * inv + bias[hl * 2];
  float vy = ay * inv + bias[hl * 2 + 1];
  if (do_relu) { vx = fmaxf(vx, 0.f); vy = fmaxf(vy, 0.f); }
  *(float2*)(out + node * 64 + hl * 2) = make_float2(vx, vy);
}

extern "C" void kernel_launch(void* const* d_in, const int* in_sizes, int n_in,
                              void* d_out, int out_size, void* d_ws, size_t ws_size,
                              hipStream_t stream) {
  const float* x = (const float*)d_in[0];
  const int* ei = (const int*)d_in[1];
  const float* W1 = (const float*)d_in[2];
  const float* att_s1 = (const float*)d_in[3];
  const float* att_d1 = (const float*)d_in[4];
  const float* b1 = (const float*)d_in[5];
  const float* W2 = (const float*)d_in[6];
  const float* att_s2 = (const float*)d_in[7];
  const float* att_d2 = (const float*)d_in[8];
  const float* b2 = (const float*)d_in[9];

  const int n = in_sizes[0] / 256;  // 100000
  const int E = in_sizes[1] / 2;    // 1600000
  const int* esrc = ei;
  const int* edst = ei + E;
  const int nbuck = (n + 255) >> 8;  // 391

  float* wsf = (float*)d_ws;
  __half* hbuf = (__half*)wsf;                  // [n*64] fp16 (region sized n*64 floats)
  float* xbuf = wsf + (long long)n * 64;        // [n*64] f32 layer-1 out / layer-2 in
  float* as_ = xbuf + (long long)n * 64;        // [n*4]
  float* ad_ = as_ + (long long)n * 4;          // [n*4]
  int* bucket_cnt = (int*)(ad_ + (long long)n * 4);  // [MAXB]
  int* bucket_base = bucket_cnt + MAXB;         // [MAXB+1]
  int* bucket_cursor = bucket_base + MAXB + 1;  // [MAXB]
  int* start = bucket_cursor + MAXB;            // [n]
  int* endp = start + n;                        // [n]
  unsigned int* pairs = (unsigned int*)(endp + n);  // [E]
  int* ccol = (int*)(pairs + E);                // [E+n]
  float* out = (float*)d_out;

  const int ebk = (E + CH - 1) / CH;  // 391 edge-chunk blocks
  const int gb = (n + 63) / 64;
  const int nb = (n + 7) / 8;  // 8 nodes per 256-thread block (2 per wave)

  // ---- CSR bucket build (shared by both layers) ----
  ifill_kernel<<<(MAXB + 255) / 256, 256, 0, stream>>>(bucket_cnt, 0, MAXB);
  bucket_hist<<<ebk, 256, 0, stream>>>(edst, E, nbuck, bucket_cnt);
  bucket_scan<<<1, 512, 0, stream>>>(bucket_cnt, bucket_base, bucket_cursor, nbuck);
  place_kernel<<<ebk, 256, 0, stream>>>(esrc, edst, E, nbuck, bucket_cursor, pairs);
  bucket_build<<<nbuck, 256, 0, stream>>>(pairs, bucket_base, ccol, start, endp, n);

  // ---- layer 1 ----
  gemm_att<256><<<gb, 256, 0, stream>>>(x, W1, att_s1, att_d1, hbuf, as_, ad_, n);
  node_agg_kernel<<<nb, 256, 0, stream>>>(ccol, start, endp, as_, ad_,
                                          (const __half2*)hbuf, b1, xbuf, n, 1);

  // ---- layer 2 ----
  gemm_att<64><<<gb, 256, 0, stream>>>(xbuf, W2, att_s2, att_d2, hbuf, as_, ad_, n);
  node_agg_kernel<<<nb, 256, 0, stream>>>(ccol, start, endp, as_, ad_,
                                          (const __half2*)hbuf, b2, out, n, 0);
}